// Round 14
// baseline (1470.187 us; speedup 1.0000x reference)
//
#include <hip/hip_runtime.h>
#include <hip/hip_bf16.h>

#define BATCH 128
#define SEQ   80
#define EMB   100
#define UNITS 2048

typedef __attribute__((ext_vector_type(8))) short bf16x8;
typedef __attribute__((ext_vector_type(4))) float f32x4;

static __device__ __forceinline__ short f2bf(float f) {
  __hip_bfloat16 h = __float2bfloat16(f);
  return *reinterpret_cast<short*>(&h);
}
static __device__ __forceinline__ float bf2f(short s) {
  __hip_bfloat16 h = *reinterpret_cast<__hip_bfloat16*>(&s);
  return __bfloat162float(h);
}

// Packed fragment layouts (nch = K/32):
//  A-pack (h, E): elem(row m, k) at [r=m>>4][kk=k>>5][lane=(m&15)|(((k>>3)&3)<<4)][j=k&7]
//  B-pack (W):    elem(k, col n) at [c=n>>4][kk=k>>5][lane=(n&15)|(((k>>3)&3)<<4)][j=k&7]
// Units of 1 KB (64 lanes x 16 B); staging is a linear 16B/lane copy.
// E and W0 zero-padded to K=256 (8 kk) so the l=0 first matmul is uniform.

__global__ __launch_bounds__(256) void pack_b_kernel(
    const float* __restrict__ src, int Ksrc, int N, int nch, int totalUnits,
    short* __restrict__ dst) {
  int lane = threadIdx.x & 63;
  int u = blockIdx.x * 4 + (threadIdx.x >> 6);
  if (u >= totalUnits) return;
  int c  = u / nch;
  int kk = u - c * nch;
  int n  = c * 16 + (lane & 15);
  int k0 = kk * 32 + ((lane >> 4) << 3);
  bf16x8 v;
#pragma unroll
  for (int j = 0; j < 8; ++j) {
    int k = k0 + j;
    float f = (k < Ksrc) ? src[k * N + n] : 0.f;
    v[j] = f2bf(f);
  }
  *reinterpret_cast<bf16x8*>(dst + (u * 64 + lane) * 8) = v;
}

// E padded to 8 kk-chunks: Ep2[t][r(8)][kq(8)][lane][8]
__global__ __launch_bounds__(256) void pack_e_kernel(
    const int* __restrict__ tokens, const float* __restrict__ emb,
    short* __restrict__ Ep2) {
  int idx = blockIdx.x * 256 + threadIdx.x;   // ((t*8+r)*8+kq)*64+lane
  if (idx >= SEQ * 8 * 8 * 64) return;
  int lane = idx & 63;
  int kq = (idx >> 6) & 7;
  int r  = (idx >> 9) & 7;
  int t  = idx >> 12;
  int b  = r * 16 + (lane & 15);
  int k0 = kq * 32 + ((lane >> 4) << 3);
  int tok = tokens[b * SEQ + t];
  bf16x8 v;
#pragma unroll
  for (int j = 0; j < 8; ++j) {
    int k = k0 + j;
    v[j] = (k < EMB) ? f2bf(emb[tok * EMB + k]) : (short)0;
  }
  *reinterpret_cast<bf16x8*>(Ep2 + (size_t)idx * 8) = v;
}

// ---------------------------------------------------------------------------
// Diagonal stage, M=128 tiles, K-split-2 across blocks (ks = which matmul):
//   ks0: P = A1 @ B1 (A1 = E[t] or h_{l-1};  B1 = W)
//   ks1: P = A2 @ B2 (A2 = h_l;              B2 = U)
// Grid 256 = 4 l x 32 cb x 2 ks; block 1024 thr = 16 waves (wr2 x wc2 x wk4).
// Each block: 128 x 64 output tile over its K (256 or 2048), BK=128,
// A-LDS ring-4 x 32 KB, B registers (asm dwordx4, depth-1), ONE barrier/step,
// exact counted vmcnt (ledger below). In-block wk reduction via LDS, then
// cross-block combine: partial written with sc0 sc1 (device-coherent at L3,
// NO cache-flushing fence), vmcnt(0), device atomicAdd on cnt[s][T]; the
// last-arriving block reads the peer partial (sc0 sc1), sums (commutative ->
// bit-deterministic), applies bias+tanh, writes h in A-pack layout.
// Correct under ANY block->XCD assignment (exchange is L3-coherent).
// ---------------------------------------------------------------------------
#define MFMA(a, b, c) __builtin_amdgcn_mfma_f32_16x16x32_bf16((a), (b), (c), 0, 0, 0)

static __device__ __forceinline__ void gload16(const void* g, void* l) {
  __builtin_amdgcn_global_load_lds(
      (const __attribute__((address_space(1))) void*)g,
      (__attribute__((address_space(3))) void*)l, 16, 0, 0);
}

struct BF { bf16x8 v[2]; };   // [y]

#define WAITV(N) asm volatile("s_waitcnt vmcnt(" #N ")" ::: "memory")

__global__ __launch_bounds__(1024) void diag_kernel(
    const short* __restrict__ Ep2,
    const short* __restrict__ W0p, const short* __restrict__ U0p,
    const short* __restrict__ Wsp, const short* __restrict__ Usp,
    const float* __restrict__ b0, const float* __restrict__ b1,
    short* __restrict__ hbase, float* __restrict__ Pbuf,
    int* __restrict__ cnt, int s) {
  __shared__ char lds[131072];   // ring-4 x 32 KB; reused for wk reduction
  __shared__ int s_last;

  const int tid  = threadIdx.x;
  const int lane = tid & 63;
  const int w    = tid >> 6;
  const int wr = w & 1, wc = (w >> 1) & 1, wk = w >> 2;

  // bid -> same-XCD ks pairs (locality heuristic only; correctness is
  // XCD-agnostic): bids of a tile differ by 8.
  int bid = blockIdx.x;
  int xcd = bid & 7, q = bid >> 3;
  int ks = q & 1, Tg = q >> 1;
  int T  = Tg * 8 + xcd;           // 0..127
  int l  = T >> 5, cb = T & 31;
  int t  = s - l;
  if (t < 0 || t >= SEQ) return;

  const size_t hsz = (size_t)8 * 64 * 64 * 8;
  const int pw = s & 1, pr = pw ^ 1;
  auto hb = [&](int ll, int p) { return hbase + (size_t)(ll * 2 + p) * hsz; };

  // ---- per-block operand config ----
  const char* Abase;
  const char* Bbase;
  int nchA, total;
  if (l == 0) {
    if (ks == 0) { Abase = (const char*)(Ep2 + (size_t)t * 32768); Bbase = (const char*)W0p; nchA = 8;  total = 2; }
    else         { Abase = (const char*)hb(0, pr);                 Bbase = (const char*)U0p; nchA = 64; total = 16; }
  } else {
    if (ks == 0) { Abase = (const char*)hb(l - 1, pr); Bbase = (const char*)Wsp; }
    else         { Abase = (const char*)hb(l, pr);     Bbase = (const char*)Usp; }
    nchA = 64; total = 16;
  }
  const size_t lb16 = (size_t)lane * 16;

  // ---- A staging: thread stages units uA (rt=uA>>2, kq=uA&3) and uA+16 ----
  const int uA = tid >> 6;
  const char* aT = Abase + ((size_t)(uA >> 2) * nchA + (uA & 3)) * 1024 + lb16;
  const size_t aHi = (size_t)4 * nchA * 1024;   // rt -> rt+4
  char* dT = &lds[0] + (size_t)uA * 1024 + lb16;

  auto issueA = [&](int g) {
    const char* src = aT + (size_t)g * 4096;
    char* dst = dT + (size_t)(g & 3) * 32768;
    gload16(src, dst);
    gload16(src + aHi, dst + 16384);
  };

  // ---- B: wave's 2 cols (cb*4 + wc*2 + {0,1}), kq = wk ----
  const char* bT0 = Bbase + ((size_t)(cb * 4 + wc * 2 + 0) * nchA + wk) * 1024 + lb16;
  const char* bT1 = Bbase + ((size_t)(cb * 4 + wc * 2 + 1) * nchA + wk) * 1024 + lb16;

#define LOADB(BN, GS)                                                         \
  do {                                                                        \
    size_t o_ = (size_t)(GS) * 4096;                                          \
    asm volatile("global_load_dwordx4 %0, %1, off" : "=v"(BN.v[0]) : "v"(bT0 + o_)); \
    asm volatile("global_load_dwordx4 %0, %1, off" : "=v"(BN.v[1]) : "v"(bT1 + o_)); \
  } while (0)

  f32x4 acc[4][2];
#pragma unroll
  for (int x = 0; x < 4; ++x)
#pragma unroll
    for (int y = 0; y < 2; ++y) acc[x][y] = (f32x4){0.f, 0.f, 0.f, 0.f};

  auto computeStep = [&](int g, const BF& Bf) {
    const char* base = &lds[0] + (size_t)(g & 3) * 32768;
#pragma unroll
    for (int x = 0; x < 4; ++x) {
      bf16x8 av = *(const bf16x8*)(base + (((size_t)(wr * 4 + x) * 4 + wk) << 10) + lb16);
      acc[x][0] = MFMA(av, Bf.v[0], acc[x][0]);
      acc[x][1] = MFMA(av, Bf.v[1], acc[x][1]);
    }
  };

  // ledger (per thread): prologue A0:2,B0:2,A1:2 = 6 outstanding.
  // STEP(g): issue B(g+1):2, A(g+2):2 -> 10; leave newest 6 (A(g),B(g) done).
  // g=total-2: issue B only -> 8; leave 4. g=total-1: leave 0.
#define STEP(G, BCUR, BNXT)                                          \
  do {                                                               \
    const int g_ = (G);                                              \
    if (g_ + 1 < total) LOADB(BNXT, g_ + 1);                         \
    if (g_ + 2 < total) issueA(g_ + 2);                              \
    if (g_ + 2 < total) { WAITV(6); }                                \
    else if (g_ + 1 < total) { WAITV(4); }                           \
    else { WAITV(0); }                                               \
    __builtin_amdgcn_s_barrier();                                    \
    __builtin_amdgcn_sched_barrier(0);                               \
    computeStep(g_, BCUR);                                           \
    __builtin_amdgcn_sched_barrier(0);                               \
  } while (0)

  BF Bq0, Bq1;
  issueA(0); LOADB(Bq0, 0); issueA(1);

  for (int g = 0; g < total; g += 2) {
    STEP(g, Bq0, Bq1);
    if (g + 1 < total) STEP(g + 1, Bq1, Bq0);
  }
#undef STEP
#undef LOADB

  // ---- in-block wk reduction: wk=1..3 -> LDS (96 KB) -> wk=0, fixed order ----
  const int wid = wr * 2 + wc;   // 0..3
  __syncthreads();
  if (wk != 0) {
    char* d = &lds[0] + ((size_t)((wk - 1) * 4 + wid) << 13);
#pragma unroll
    for (int x = 0; x < 4; ++x)
#pragma unroll
      for (int y = 0; y < 2; ++y)
        *(f32x4*)(d + (((x * 2 + y) << 10) + lb16)) = acc[x][y];
  }
  __syncthreads();
  if (wk == 0) {
#pragma unroll
    for (int p = 0; p < 3; ++p) {
      const char* sp = &lds[0] + ((size_t)(p * 4 + wid) << 13);
#pragma unroll
      for (int x = 0; x < 4; ++x)
#pragma unroll
        for (int y = 0; y < 2; ++y)
          acc[x][y] += *(const f32x4*)(sp + (((x * 2 + y) << 10) + lb16));
    }
    // ---- write partial, device-coherent (sc0 sc1 -> L3), no fence ----
    char* Pown = (char*)Pbuf + ((size_t)T * 2 + ks) * 32768 + ((size_t)wid << 13) + lb16;
#pragma unroll
    for (int x = 0; x < 4; ++x)
#pragma unroll
      for (int y = 0; y < 2; ++y)
        asm volatile("global_store_dwordx4 %0, %1, off sc0 sc1"
                     :: "v"(Pown + ((x * 2 + y) << 10)), "v"(acc[x][y]) : "memory");
  }
  WAITV(0);                      // own stores acked at coherence point
  __syncthreads();               // all wk0 stores done before the atomic
  if (tid == 0) s_last = (atomicAdd(&cnt[s * 128 + T], 1) == 1);
  __syncthreads();
  if (!s_last) return;
  if (wk != 0) return;

  // ---- last block: read peer partial (sc0 sc1), combine, epilogue ----
  const char* Ppeer = (const char*)Pbuf + ((size_t)T * 2 + (ks ^ 1)) * 32768 + ((size_t)wid << 13) + lb16;
  f32x4 pv[4][2];
#pragma unroll
  for (int x = 0; x < 4; ++x)
#pragma unroll
    for (int y = 0; y < 2; ++y)
      asm volatile("global_load_dwordx4 %0, %1, off sc0 sc1"
                   : "=v"(pv[x][y]) : "v"(Ppeer + ((x * 2 + y) << 10)) : "memory");
  WAITV(0);
#pragma unroll
  for (int x = 0; x < 4; ++x)
#pragma unroll
    for (int y = 0; y < 2; ++y)
      acc[x][y] += pv[x][y];     // commutative -> deterministic either way

  // bias + tanh -> h (A-pack layout), parity pw.
  // C/D layout: col = lane&15, row = (lane>>4)*4 + i.
  const float* bias = (l == 0) ? b0 : b1;
  short* H = hb(l, pw);
  const int lo = lane & 15, hi = lane >> 4;
  const int nb = cb * 64 + wc * 32;
  const float bv0 = bias[nb + lo];
  const float bv1 = bias[nb + 16 + lo];
#pragma unroll
  for (int x = 0; x < 4; ++x)
#pragma unroll
    for (int y = 0; y < 2; ++y) {
      float bbv = y ? bv1 : bv0;
#pragma unroll
      for (int i = 0; i < 4; ++i) {
        int m = wr * 64 + x * 16 + hi * 4 + i;
        int n = nb + y * 16 + lo;
        float z = acc[x][y][i] + bbv;
        float e = __expf(2.f * z);
        float th = 1.f - 2.f / (e + 1.f);
        int rr = m >> 4, kk = n >> 5;
        int lp = (m & 15) | (((n >> 3) & 3) << 4);
        H[(((size_t)rr * 64 + kk) * 64 + lp) * 8 + (n & 7)] = f2bf(th);
      }
    }
}

// ---------------------------------------------------------------------------
// Output head: out[b] = sigmoid(h3[b] . Wo + bo); h3 in A-pack layout.
// ---------------------------------------------------------------------------
__global__ __launch_bounds__(256) void head_kernel(
    const short* __restrict__ h3, const float* __restrict__ Wo,
    const float* __restrict__ bo, float* __restrict__ out) {
  __shared__ float sred[4];
  int b = blockIdx.x, tid = threadIdx.x;
  int kk = tid >> 2, hi = tid & 3;
  const bf16x8 v = *reinterpret_cast<const bf16x8*>(
      h3 + (((size_t)(b >> 4) * 64 + kk) * 64 + ((b & 15) | (hi << 4))) * 8);
  int k0 = kk * 32 + hi * 8;
  float acc = 0.f;
#pragma unroll
  for (int j = 0; j < 8; ++j) acc += bf2f(v[j]) * Wo[k0 + j];
  for (int off = 32; off > 0; off >>= 1) acc += __shfl_down(acc, off);
  if ((tid & 63) == 0) sred[tid >> 6] = acc;
  __syncthreads();
  if (tid == 0) {
    float z = sred[0] + sred[1] + sred[2] + sred[3] + bo[0];
    out[b] = 1.f / (1.f + expf(-z));
  }
}

extern "C" void kernel_launch(void* const* d_in, const int* in_sizes, int n_in,
                              void* d_out, int out_size, void* d_ws, size_t ws_size,
                              hipStream_t stream) {
  const int*   tokens = (const int*)d_in[0];
  const float* emb    = (const float*)d_in[1];
  const float* W0     = (const float*)d_in[2];
  const float* U0     = (const float*)d_in[3];
  const float* b0     = (const float*)d_in[4];
  const float* W1     = (const float*)d_in[5];
  const float* U1     = (const float*)d_in[6];
  const float* b1     = (const float*)d_in[7];
  const float* Wo     = (const float*)d_in[8];
  const float* bo     = (const float*)d_in[9];
  float* out = (float*)d_out;
  char*  ws  = (char*)d_ws;

  // byte offsets
  const size_t W0P_OFF = 0;                                 // 1 MB (8 kk pad)
  const size_t U0P_OFF = W0P_OFF + 1048576;
  const size_t W1P_OFF = U0P_OFF + 8388608;
  const size_t U1P_OFF = W1P_OFF + 8388608;
  const size_t EP_OFF  = U1P_OFF + 8388608;                 // 5 MB
  const size_t H_OFF   = EP_OFF + 5242880;                  // 4 MB
  const size_t P_OFF   = H_OFF + 4194304;                   // 8 MB partials
  const size_t C_OFF   = P_OFF + 8388608;                   // counters

  short* W0p = (short*)(ws + W0P_OFF);
  short* U0p = (short*)(ws + U0P_OFF);
  short* W1p = (short*)(ws + W1P_OFF);
  short* U1p = (short*)(ws + U1P_OFF);
  short* Ep2 = (short*)(ws + EP_OFF);
  short* hbase = (short*)(ws + H_OFF);
  float* Pbuf  = (float*)(ws + P_OFF);
  int*   cnt   = (int*)(ws + C_OFF);
  const size_t H_SZ = (size_t)8 * 64 * 64 * 8;   // shorts per h buffer

  {
    int unitsW0 = (UNITS / 16) * 8;             // 1024 (8 kk, zero-padded)
    pack_b_kernel<<<(unitsW0 + 3) / 4, 256, 0, stream>>>(W0, EMB, UNITS, 8, unitsW0, W0p);
    int unitsU = (UNITS / 16) * (UNITS / 32);   // 8192
    pack_b_kernel<<<(unitsU + 3) / 4, 256, 0, stream>>>(U0, UNITS, UNITS, UNITS / 32, unitsU, U0p);
    pack_b_kernel<<<(unitsU + 3) / 4, 256, 0, stream>>>(W1, UNITS, UNITS, UNITS / 32, unitsU, W1p);
    pack_b_kernel<<<(unitsU + 3) / 4, 256, 0, stream>>>(U1, UNITS, UNITS, UNITS / 32, unitsU, U1p);
    int ne = SEQ * 8 * 8 * 64;
    pack_e_kernel<<<(ne + 255) / 256, 256, 0, stream>>>(tokens, emb, Ep2);
  }

  // zero h double-buffers (h_l[-1] = 0) and per-diagonal tile counters
  hipMemsetAsync(hbase, 0, 8u * 262144u * 2u, stream);
  hipMemsetAsync(cnt, 0, (size_t)83 * 128 * 4, stream);

  // ---- 83 diagonals: s = t + l ----
  for (int s = 0; s <= SEQ - 1 + 3; ++s) {
    diag_kernel<<<256, 1024, 0, stream>>>(Ep2, W0p, U0p, W1p, U1p, b0, b1,
                                          hbase, Pbuf, cnt, s);
  }

  // final head: h3[SEQ-1] written at diagonal 82 (parity 0)
  head_kernel<<<BATCH, 256, 0, stream>>>(hbase + 6 * H_SZ, Wo, bo, out);
}